// Round 11
// baseline (120.166 us; speedup 1.0000x reference)
//
#include <hip/hip_runtime.h>

// QueryEncDec: 2 stacks x 128 layers of scalar GRU (H=in=1), T=256.
// R11 = R10 (4 waves x 64 lanes, 3-phase loop, DPP handoff w/ old-operand
// feed, collector flush every 4 steps) plus:
//  1. Newton reciprocal for the TWO on-chain rcps (r and q): int-magic seed
//     (0x7EF311C3 - bits) + 2 Newton iters = 20 cy chain vs ~30 for v_rcp.
//     Relative error ~4e-5 (contractive chain -> no accumulation).
//     z-gate keeps hardware rcp (off the critical chain).
//  2. Batch-4 mailbox reads with one-batch prefetch: ds_read for batch b+1
//     issued at batch b's start (~650 cy early) -> boundary stalls ~0.
//     Flush cadence unchanged (every 4 steps, lanes 60..63, si==2), so
//     publication delay <= 66, prefetch needs lag >= 73, pre-spin gives 74:
//     critical path stays 3*74+320 = 542 steps.

#define T_LEN 256
#define MBOX  320              // 0..255 data slots, 256..319 per-lane dump
typedef unsigned long long u64;
typedef unsigned int u32;

__device__ __forceinline__ float fexp2(float x) { return __builtin_amdgcn_exp2f(x); }
__device__ __forceinline__ float frcp(float x)  { return __builtin_amdgcn_rcpf(x); }

// 1/d via integer-magic seed + 2 Newton iterations (d in [1, ~1e6] here).
// Chain: int-sub(4) + 2*(fma+mul)(16) = 20 cy; rel err ~4e-5.
__device__ __forceinline__ float newton_rcp(float d) {
    const u32 sb = 0x7EF311C3u - __builtin_bit_cast(u32, d);
    float r = __builtin_bit_cast(float, sb);
    r = r * __builtin_fmaf(-d, r, 2.0f);
    r = r * __builtin_fmaf(-d, r, 2.0f);
    return r;
}

struct CellW {
    float wri, wrh, brc;   // r gate, pre-scaled by -log2(e)
    float wzi, wzh, bzc;   // z gate, pre-scaled by -log2(e)
    float wni, bni;        // n gate input half, pre-scaled by 2*log2(e)
    float wnh, bnh;        // n gate hidden half, pre-scaled by 2*log2(e)
};

__device__ __forceinline__ float cell_step(const CellW& c, float x, float h) {
    // h-leg pre-sums run while x is still in the DPP; x enters 1 fma deep.
    const float hr  = __builtin_fmaf(c.wrh, h, c.brc);
    const float hz  = __builtin_fmaf(c.wzh, h, c.bzc);
    const float ghn = __builtin_fmaf(c.wnh, h, c.bnh);
    const float gin = __builtin_fmaf(c.wni, x, c.bni);
    const float er  = fexp2(__builtin_fmaf(c.wri, x, hr));
    const float ez  = fexp2(__builtin_fmaf(c.wzi, x, hz));
    const float r   = newton_rcp(1.0f + er);        // on-chain: Newton
    const float z   = frcp(1.0f + ez);              // off-chain: hw rcp
    const float en  = fexp2(__builtin_fmaf(r, ghn, gin));  // e^{2v}
    const float q   = newton_rcp(1.0f + en);        // on-chain: Newton
    const float A   = __builtin_fmaf(z, h - 1.0f, 1.0f);
    const float B   = __builtin_fmaf(2.0f, z, -2.0f);
    return __builtin_fmaf(q, B, A);                 // (1-z)n + z h
}

template<bool MASKED, bool READ, bool LAST>
__device__ __forceinline__ void do_batch4(
    const int s0, const int j, const int js, const CellW& c,
    volatile u64* inbox, volatile u64* outbox,
    float* __restrict__ out, float* __restrict__ dumpG,
    float& h, float& hcp, u32& coll, u64& bnext)
{
    u32 bval = 0;
    if (READ) {
        const int slot = s0 + js;
        u64 v = bnext;                  // prefetched one batch (~650 cy) ago
        while (__ballot((u32)(v >> 32) == (u32)(slot + 1)) != ~0ull)
            v = inbox[slot];            // cold fallback (fill only)
        bval = (u32)v;
        if (s0 + 4 < T_LEN) bnext = inbox[s0 + 4 + js];   // prefetch next
    }
    #pragma unroll
    for (int si = 0; si < 4; ++si) {
        const int s = s0 + si;
        // lane-0 feed (literal-index readlane); handoff via DPP old-operand
        const int fv = READ ? __builtin_amdgcn_readlane((int)bval, si) : 0;
        const int xm = __builtin_amdgcn_update_dpp(
            fv, __builtin_bit_cast(int, hcp), 0x138 /*wave_shr:1*/, 0xF, 0xF, false);
        const float x = __builtin_bit_cast(float, xm);

        const float hc = cell_step(c, x, h);
        if (MASKED) {
            const int t = s - j;
            h = ((u32)t < (u32)T_LEN) ? hc : h;
        } else {
            h = hc;                     // steady: always in-range
        }
        hcp = hc;

        // collector: shift history DOWN (lane m <- m+1), insert committed h
        const int cs = __builtin_amdgcn_update_dpp(
            0, (int)coll, 0x130 /*wave_shl:1*/, 0xF, 0xF, false);
        coll = (j == 63) ? __builtin_bit_cast(u32, h) : (u32)cs;

        if (si == 2) {                  // flush every 4 steps (compile-time)
            // lane m in 60..63 holds lane-63 h for t = s + m - 126
            const int  tm   = s + j - 126;
            const bool real = (j >= 60) & (tm >= 0);
            if (!LAST) {
                const int widx = real ? tm : (T_LEN + j);    // dump: 256+j
                outbox[widx] = ((u64)(u32)(tm + 1) << 32) | (u64)coll;
            } else {                    // dec_out: coalesced 4-float store
                float* p = real ? (out + tm) : (dumpG + j);
                *p = __builtin_bit_cast(float, coll);
            }
        }
    }
}

template<bool LAST>
__device__ __forceinline__ float run_wave(
    const int j, const CellW& c,
    volatile u64* inbox, volatile u64* outbox,
    float* __restrict__ out, float* __restrict__ dumpG)
{
    float h = 0.0f, hcp = 0.0f;
    u32 coll = 0;
    const int js = j & 3;

    // pre-spin: slot 11 (tag 12) is published at producer local step 74 ->
    // lag >= 74; prefetch of slot s0+4+js needs lag >= 70+js (js<=3): OK.
    // Wave 0's inbox is the pre-tagged X mailbox: passes immediately.
    {
        u64 v = inbox[11];
        while (__ballot((u32)(v >> 32) == 12u) != ~0ull) v = inbox[11];
    }
    u64 bnext = inbox[js];              // prefetch batch 0

    #pragma unroll 1
    for (int b = 0; b < 16; ++b)        // prologue: s = 0..63 (masked, reads)
        do_batch4<true, true, LAST>(b * 4, j, js, c, inbox, outbox, out, dumpG, h, hcp, coll, bnext);
    #pragma unroll 1
    for (int b = 16; b < 64; ++b)       // steady: s = 64..255 (unmasked, reads)
        do_batch4<false, true, LAST>(b * 4, j, js, c, inbox, outbox, out, dumpG, h, hcp, coll, bnext);
    #pragma unroll 1
    for (int b = 64; b < 80; ++b)       // epilogue: s = 256..319 (masked, no reads)
        do_batch4<true, false, LAST>(b * 4, j, js, c, inbox, outbox, out, dumpG, h, hcp, coll, bnext);

    return h;
}

__global__ __launch_bounds__(256, 1) void gru_pipe11(
    const float* __restrict__ X,
    const float* __restrict__ enc_w_ih, const float* __restrict__ enc_w_hh,
    const float* __restrict__ enc_b_ih, const float* __restrict__ enc_b_hh,
    const float* __restrict__ dec_w_ih, const float* __restrict__ dec_w_hh,
    const float* __restrict__ dec_b_ih, const float* __restrict__ dec_b_hh,
    float* __restrict__ out, float* __restrict__ dumpG)
{
    const int tid = threadIdx.x;        // global layer 0..255
    const int w   = tid >> 6;           // wave 0..3
    const int j   = tid & 63;

    __shared__ u64 xsM[T_LEN];          // X as a pre-tagged mailbox
    __shared__ u64 box[4][MBOX];        // box[3] = wave-3 trash (uniform code path)

    xsM[tid] = ((u64)(u32)(tid + 1) << 32) |
               (u64)__builtin_bit_cast(u32, X[tid]);
    box[0][tid] = 0ull;                 // data slots 0..255 need tag=0
    box[1][tid] = 0ull;
    box[2][tid] = 0ull;
    box[3][tid] = 0ull;

    // per-layer params (torch gate order r,z,n), constants folded
    const int pl = tid & 127;
    const float* wip = (tid < 128) ? enc_w_ih : dec_w_ih;
    const float* whp = (tid < 128) ? enc_w_hh : dec_w_hh;
    const float* bip = (tid < 128) ? enc_b_ih : dec_b_ih;
    const float* bhp = (tid < 128) ? enc_b_hh : dec_b_hh;
    const float L2E = 1.44269504088896340736f;
    CellW c;
    c.wri = -L2E * wip[3 * pl + 0];
    c.wrh = -L2E * whp[3 * pl + 0];
    c.brc = -L2E * (bip[3 * pl + 0] + bhp[3 * pl + 0]);
    c.wzi = -L2E * wip[3 * pl + 1];
    c.wzh = -L2E * whp[3 * pl + 1];
    c.bzc = -L2E * (bip[3 * pl + 1] + bhp[3 * pl + 1]);
    c.wni = 2.0f * L2E * wip[3 * pl + 2];
    c.bni = 2.0f * L2E * bip[3 * pl + 2];
    c.wnh = 2.0f * L2E * whp[3 * pl + 2];
    c.bnh = 2.0f * L2E * bhp[3 * pl + 2];

    __syncthreads();                    // the only block barrier

    volatile u64* inbox  = (w == 0) ? xsM : box[w - 1];
    volatile u64* outbox = box[w];

    float h;
    if (w == 3) h = run_wave<true >(j, c, inbox, outbox, out, dumpG);
    else        h = run_wave<false>(j, c, inbox, outbox, out, dumpG);

    // dec_h: final hidden of decoder layers (global layers 128..255)
    if (w >= 2) out[T_LEN + 64 * (w - 2) + j] = h;
}

extern "C" void kernel_launch(void* const* d_in, const int* in_sizes, int n_in,
                              void* d_out, int out_size, void* d_ws, size_t ws_size,
                              hipStream_t stream) {
    const float* X        = (const float*)d_in[0];
    const float* enc_w_ih = (const float*)d_in[1];
    const float* enc_w_hh = (const float*)d_in[2];
    const float* enc_b_ih = (const float*)d_in[3];
    const float* enc_b_hh = (const float*)d_in[4];
    const float* dec_w_ih = (const float*)d_in[5];
    const float* dec_w_hh = (const float*)d_in[6];
    const float* dec_b_ih = (const float*)d_in[7];
    const float* dec_b_hh = (const float*)d_in[8];
    float* out = (float*)d_out;
    float* dumpG = (float*)d_ws;

    gru_pipe11<<<1, 256, 0, stream>>>(X,
                                      enc_w_ih, enc_w_hh, enc_b_ih, enc_b_hh,
                                      dec_w_ih, dec_w_hh, dec_b_ih, dec_b_hh,
                                      out, dumpG);
}